// Round 17
// baseline (16642.612 us; speedup 1.0000x reference)
//
#include <hip/hip_runtime.h>

#define VOCABN 401
#define EN 256
#define HN 768
#define H3N 2304
#define ON 3
#define BN 64
#define TN 1024

// 8 replicas (8 batches each) x 12 WGs (64 j each); WG = 4 waves, 1 wave/SIMD.
// Wave owns 16 j x 3 gates x full K=768 in 288 weight VGPRs.
#define NREP 8
#define WGR  12
#define BPR  8
#define NTH  256

typedef _Float16 f16x8 __attribute__((ext_vector_type(8)));
typedef float f32x4 __attribute__((ext_vector_type(4)));
typedef unsigned long long u64;

// workgroup barrier draining ONLY lgkm — in-flight global loads survive.
__device__ __forceinline__ void barrier_lgkm() {
    asm volatile("s_waitcnt lgkmcnt(0)\n\ts_barrier" ::: "memory");
}

// ---------------- K1: gtab[v][g] = dot(embed[v], W_ih[g]) + b_ih[g]  (w-stationary)
__global__ __launch_bounds__(256)
void k_build_gtab(const float* __restrict__ embed, const float* __restrict__ wih,
                  const float* __restrict__ bih, float* __restrict__ gtab) {
    const int g  = blockIdx.x * 64 + (threadIdx.x >> 2);
    const int ql = threadIdx.x & 3;
    const int v0 = blockIdx.y * 26;
    const int v1 = min(VOCABN, v0 + 26);
    float4 w[16];
    const float4* s4 = (const float4*)(wih + (size_t)g * EN + ql * 64);
#pragma unroll
    for (int i = 0; i < 16; ++i) w[i] = s4[i];
    const float bias = bih[g];
    for (int v = v0; v < v1; ++v) {
        const float4* e4 = (const float4*)(embed + (size_t)v * EN + ql * 64);
        float acc = 0.f;
#pragma unroll
        for (int i = 0; i < 16; ++i) {
            float4 e = e4[i];
            acc += w[i].x * e.x + w[i].y * e.y + w[i].z * e.z + w[i].w * e.w;
        }
        acc += __shfl_xor(acc, 1, 64);
        acc += __shfl_xor(acc, 2, 64);
        if (ql == 0) gtab[(size_t)v * H3N + g] = acc + bias;
    }
}

// ---------------- K2: wave-autonomous persistent-weight recurrence.
// Sub-stage (t, b): [tid<128: verify 3 pre-issued tagged u64, deposit tile[b&1],
// issue loads for next sub-stage; all: x-prefetch for next] | barrier(lgkm) |
// [each wave: 24 ds_read_b128 (broadcast) + 72 MFMA full-K -> complete sums in D;
// in-lane gates for 4 j; 2 tagged u64 stores (lanes lane&15==0)].
// Tag protocol as r9-r16; anti-overwrite: my-store(t+1,b) follows my-verify(t,b)
// follows every peer's store(t,b) follows its read of (t-1,b). memset-0 == t=0.
__global__ __launch_bounds__(NTH, 1)
void k_rnn(const int* __restrict__ tokens, const float* __restrict__ whh,
           const float* __restrict__ gtab, const float* __restrict__ bhh,
           unsigned* __restrict__ hbuf, float* __restrict__ hout) {
    const int R    = blockIdx.x & (NREP - 1);   // replica
    const int wgj  = blockIdx.x >> 3;           // 0..11, owns j in [wgj*64, wgj*64+64)
    const int tid  = threadIdx.x;
    const int lane = tid & 63;
    const int jb   = tid >> 6;                  // wave 0..3
    const int j_tile = wgj * 64 + jb * 16;
    const int rowl = lane & 15;
    const int kg   = lane >> 4;                 // 0..3
    const int jx   = j_tile + kg * 4;           // this lane's first j (gate rows)

    __shared__ int stok[BPR][TN];                    // 32768 B
    __shared__ __align__(16) _Float16 hT[2][HN];     // 3072 B

    for (int i = tid; i < BPR * TN; i += NTH)
        stok[i >> 10][i & 1023] = tokens[(size_t)(R * BPR + (i >> 10)) * TN + (i & 1023)];

    // ---- one-time: full-K weight fragments: 72 f16x8 = 288 VGPRs.
    // A layout (m89/r13-proven): row = lane&15 within tile, k = ks*32 + kg*8 + i.
    f16x8 a[3][24];
#pragma unroll
    for (int g = 0; g < 3; ++g) {
        const float* wsrc = whh + (size_t)(g * HN + j_tile + rowl) * HN;
#pragma unroll
        for (int ks = 0; ks < 24; ++ks) {
            const float4* p4 = (const float4*)(wsrc + ks * 32 + kg * 8);
            float4 x0 = p4[0], x1 = p4[1];
            f16x8 tf;
            tf[0]=(_Float16)x0.x; tf[1]=(_Float16)x0.y; tf[2]=(_Float16)x0.z; tf[3]=(_Float16)x0.w;
            tf[4]=(_Float16)x1.x; tf[5]=(_Float16)x1.y; tf[6]=(_Float16)x1.z; tf[7]=(_Float16)x1.w;
            a[g][ks] = tf;
        }
    }
    const float4 bR = *(const float4*)(bhh + jx);
    const float4 bZ = *(const float4*)(bhh + HN + jx);
    const float4 bN = *(const float4*)(bhh + 2 * HN + jx);

    u64* hb2 = (u64*)hbuf + (size_t)R * (2 * BPR * 384);

    u64 v[2][3] = {0, 0, 0, 0, 0, 0};
    float4 xR[2], xZ[2], xN[2];
    xR[0] = xR[1] = xZ[0] = xZ[1] = xN[0] = xN[1] = float4{0, 0, 0, 0};

    // prologue: issue loads for sub-stage 0 (b=0, t=0; memset zeros = tag 0)
    if (tid < 128) {
#pragma unroll
        for (int q = 0; q < 3; ++q)
            v[0][q] = __hip_atomic_load(hb2 + 3 * tid + q,
                                        __ATOMIC_RELAXED, __HIP_MEMORY_SCOPE_AGENT);
    }
    __syncthreads();                        // stok staged
    {
        const int tok = stok[0][0];
        const float* g_ = gtab + (size_t)tok * H3N;
        xR[0] = *(const float4*)(g_ + jx);
        xZ[0] = *(const float4*)(g_ + HN + jx);
        xN[0] = *(const float4*)(g_ + 2 * HN + jx);
    }

#pragma unroll 1
    for (int t = 0; t < TN; ++t) {
        const u64 want = ((u64)(unsigned)t << 16) | ((u64)(unsigned)t << 48);
#pragma unroll 2
        for (int b8 = 0; b8 < BPR; ++b8) {
            const int sp = b8 & 1, sn = sp ^ 1;
            // ---- verify (first-try in steady state: 7 sub-stages of slack) + deposit
            if (tid < 128) {
#pragma unroll
                for (int q = 0; q < 3; ++q) {
                    const u64* cur = hb2 + (t & 1) * 3072 + b8 * 384 + 3 * tid + q;
                    u64 vv = v[sp][q];
                    while ((vv & 0xFFFF0000FFFF0000ull) != want) {
                        __builtin_amdgcn_s_sleep(1);
                        vv = __hip_atomic_load(cur, __ATOMIC_RELAXED, __HIP_MEMORY_SCOPE_AGENT);
                    }
                    ((unsigned*)hT[sp])[3 * tid + q] =
                        __builtin_amdgcn_perm((unsigned)(vv >> 32), (unsigned)vv, 0x05040100);
                }
            }
            // ---- issue next sub-stage's loads + x-prefetch (consumed after next barrier)
            int b1 = b8 + 1;
            const int t1 = t + (b1 >> 3);
            b1 &= 7;
            if (t1 < TN) {
                if (tid < 128) {
#pragma unroll
                    for (int q = 0; q < 3; ++q)
                        v[sn][q] = __hip_atomic_load(
                            hb2 + (t1 & 1) * 3072 + b1 * 384 + 3 * tid + q,
                            __ATOMIC_RELAXED, __HIP_MEMORY_SCOPE_AGENT);
                }
                const int tok = stok[b1][t1];
                const float* g_ = gtab + (size_t)tok * H3N;
                xR[sn] = *(const float4*)(g_ + jx);
                xZ[sn] = *(const float4*)(g_ + HN + jx);
                xN[sn] = *(const float4*)(g_ + 2 * HN + jx);
            }
            barrier_lgkm();                 // tile[sp] ready; global loads in flight

            // ---- full-K dot on matrix pipe: 24 broadcast reads + 72 MFMA
            f32x4 ar = {0, 0, 0, 0}, az = {0, 0, 0, 0}, an = {0, 0, 0, 0};
#pragma unroll
            for (int ks = 0; ks < 24; ++ks) {
                f16x8 bf = *(const f16x8*)(&hT[sp][ks * 32 + kg * 8]);
                ar = __builtin_amdgcn_mfma_f32_16x16x32_f16(a[0][ks], bf, ar, 0, 0, 0);
                az = __builtin_amdgcn_mfma_f32_16x16x32_f16(a[1][ks], bf, az, 0, 0, 0);
                an = __builtin_amdgcn_mfma_f32_16x16x32_f16(a[2][ks], bf, an, 0, 0, 0);
            }
            // ---- in-lane gates for 4 j (D row=(lane>>4)*4+r; cols redundant)
            const _Float16* hop = &hT[sp][jx];
            unsigned pk[4];
            float hnewf[4];
#pragma unroll
            for (int r = 0; r < 4; ++r) {
                const float sr = ar[r] + ((const float*)&bR)[r];
                const float sz = az[r] + ((const float*)&bZ)[r];
                const float sn_ = an[r] + ((const float*)&bN)[r];
                const float xr = ((const float*)&xR[sp])[r];
                const float xz = ((const float*)&xZ[sp])[r];
                const float xn = ((const float*)&xN[sp])[r];
                const float rr = 1.f / (1.f + __expf(-(xr + sr)));
                const float zz = 1.f / (1.f + __expf(-(xz + sz)));
                const float nx = xn + rr * sn_;
                const float nn = 1.f - 2.f / (__expf(2.f * nx) + 1.f);   // tanh
                const float ho = (float)hop[r];
                const float hn = (1.f - zz) * nn + zz * ho;
                hnewf[r] = hn;
                pk[r] = ((unsigned)(t + 1) << 16)
                      | (unsigned)__builtin_bit_cast(unsigned short, (_Float16)hn);
            }
            if ((lane & 15) == 0) {          // one col-copy publishes
                if (t < TN - 1) {
                    u64* dst = hb2 + ((t + 1) & 1) * 3072 + b8 * 384 + (jx >> 1);
                    __hip_atomic_store(dst,     (u64)pk[0] | ((u64)pk[1] << 32),
                                       __ATOMIC_RELAXED, __HIP_MEMORY_SCOPE_AGENT);
                    __hip_atomic_store(dst + 1, (u64)pk[2] | ((u64)pk[3] << 32),
                                       __ATOMIC_RELAXED, __HIP_MEMORY_SCOPE_AGENT);
                } else {
                    float* ho_ = hout + (size_t)(R * BPR + b8) * HN + jx;
                    ho_[0] = hnewf[0]; ho_[1] = hnewf[1];
                    ho_[2] = hnewf[2]; ho_[3] = hnewf[3];
                }
            }
        }
    }
}

// ---------------- K3: logits + log_softmax
__global__ void k_logits(const float* __restrict__ hfin, const float* __restrict__ wout,
                         const float* __restrict__ bout, float* __restrict__ lp) {
    const int b = blockIdx.x;
    const int o = threadIdx.x / 64;
    const int lane = threadIdx.x % 64;
    const float* hrow = hfin + (size_t)b * HN;
    const float* w = wout + (size_t)o * HN;
    float p = 0.f;
    for (int k = lane; k < HN; k += 64) p += hrow[k] * w[k];
    for (int off = 32; off > 0; off >>= 1) p += __shfl_down(p, off, 64);
    __shared__ float lg[ON];
    if (lane == 0) lg[o] = p + bout[o];
    __syncthreads();
    if (threadIdx.x == 0) {
        float m = fmaxf(lg[0], fmaxf(lg[1], lg[2]));
        float s = __expf(lg[0] - m) + __expf(lg[1] - m) + __expf(lg[2] - m);
        float ls = __logf(s);
        lp[b * ON + 0] = lg[0] - m - ls;
        lp[b * ON + 1] = lg[1] - m - ls;
        lp[b * ON + 2] = lg[2] - m - ls;
    }
}

extern "C" void kernel_launch(void* const* d_in, const int* in_sizes, int n_in,
                              void* d_out, int out_size, void* d_ws, size_t ws_size,
                              hipStream_t stream) {
    const int*   tokens = (const int*)d_in[0];
    // d_in[1] = hidden: reference zeroes it, ignored.
    const float* embed  = (const float*)d_in[2];
    const float* wih    = (const float*)d_in[3];
    const float* whh    = (const float*)d_in[4];
    const float* bih    = (const float*)d_in[5];
    const float* bhh    = (const float*)d_in[6];
    const float* wout   = (const float*)d_in[7];
    const float* bout   = (const float*)d_in[8];

    float* out = (float*)d_out;                  // [B*O logprobs][B*H h_final]
    char* ws = (char*)d_ws;
    const size_t GTAB_OFF = 0;                   // 401*2304*4 = 3,695,616
    const size_t HBUF_OFF = 3695616;             // 8*2*8*384*8 = 393,216 (tagged u64)
    float*    gtab = (float*)(ws + GTAB_OFF);
    unsigned* hbuf = (unsigned*)(ws + HBUF_OFF);

    // tag protocol requires tag==0 / h==0 state on EVERY launch (graph-replayed)
    hipMemsetAsync(ws + HBUF_OFF, 0, 393216, stream);

    hipLaunchKernelGGL(k_build_gtab, dim3(H3N / 64, 16), dim3(256), 0, stream,
                       embed, wih, bih, gtab);
    hipLaunchKernelGGL(k_rnn, dim3(NREP * WGR), dim3(NTH), 0, stream,
                       tokens, whh, gtab, bhh, hbuf, out + BN * ON);
    hipLaunchKernelGGL(k_logits, dim3(BN), dim3(192), 0, stream,
                       out + BN * ON, wout, bout, out);
}

// Round 18
// 16514.055 us; speedup vs baseline: 1.0078x; 1.0078x over previous
//
#include <hip/hip_runtime.h>

#define VOCABN 401
#define EN 256
#define HN 768
#define H3N 2304
#define ON 3
#define BN 64
#define TN 1024

// 32 replicas x 16 WGs; WG = 768 threads: 48 j's x 16 k-slices; 2 staged batches.
// 512 WGs = 2 WG/CU (24 waves/CU).
#define NREP 32
#define WGPR 16
#define BPR  2
#define JPW  48
#define NTH  768

typedef _Float16 f16x2 __attribute__((ext_vector_type(2)));
typedef _Float16 f16x8 __attribute__((ext_vector_type(8)));
typedef unsigned long long u64;
union F16x8 { f16x8 v; f16x2 p[4]; };

__device__ __forceinline__ float fdot2(f16x2 a, f16x2 b, float c) {
#if __has_builtin(__builtin_amdgcn_fdot2)
    return __builtin_amdgcn_fdot2(a, b, c, false);
#else
    return c + (float)a[0] * (float)b[0] + (float)a[1] * (float)b[1];
#endif
}

// workgroup barrier draining ONLY lgkm — in-flight global (poll) loads survive.
__device__ __forceinline__ void barrier_lgkm() {
    asm volatile("s_waitcnt lgkmcnt(0)\n\ts_barrier" ::: "memory");
}

// sum across each aligned 16-lane group; pure-VALU DPP butterfly.
__device__ __forceinline__ float hexsum(float x) {
    int v = __builtin_bit_cast(int, x);
    x += __builtin_bit_cast(float, __builtin_amdgcn_update_dpp(0, v, 0xB1, 0xF, 0xF, true));
    v = __builtin_bit_cast(int, x);
    x += __builtin_bit_cast(float, __builtin_amdgcn_update_dpp(0, v, 0x4E, 0xF, 0xF, true));
    v = __builtin_bit_cast(int, x);
    x += __builtin_bit_cast(float, __builtin_amdgcn_update_dpp(0, v, 0x141, 0xF, 0xF, true));
    v = __builtin_bit_cast(int, x);
    x += __builtin_bit_cast(float, __builtin_amdgcn_update_dpp(0, v, 0x140, 0xF, 0xF, true));
    return x;
}

// ---------------- K1: gtab[v][g] = dot(embed[v], W_ih[g]) + b_ih[g]  (w-stationary)
__global__ __launch_bounds__(256)
void k_build_gtab(const float* __restrict__ embed, const float* __restrict__ wih,
                  const float* __restrict__ bih, float* __restrict__ gtab) {
    const int g  = blockIdx.x * 64 + (threadIdx.x >> 2);
    const int ql = threadIdx.x & 3;
    const int v0 = blockIdx.y * 26;
    const int v1 = min(VOCABN, v0 + 26);
    float4 w[16];
    const float4* s4 = (const float4*)(wih + (size_t)g * EN + ql * 64);
#pragma unroll
    for (int i = 0; i < 16; ++i) w[i] = s4[i];
    const float bias = bih[g];
    for (int v = v0; v < v1; ++v) {
        const float4* e4 = (const float4*)(embed + (size_t)v * EN + ql * 64);
        float acc = 0.f;
#pragma unroll
        for (int i = 0; i < 16; ++i) {
            float4 e = e4[i];
            acc += w[i].x * e.x + w[i].y * e.y + w[i].z * e.z + w[i].w * e.w;
        }
        acc += __shfl_xor(acc, 1, 64);
        acc += __shfl_xor(acc, 2, 64);
        if (ql == 0) gtab[(size_t)v * H3N + g] = acc + bias;
    }
}

// ---------------- K2: persistent-weight recurrence; 2-stage batch stagger (minimum),
// depth-2 poll ring, lgkm-only barriers. Structure = r12 (best) with BPR 4->2.
// h word (u32): [31:16]=step tag, [15:0]=f16 bits; u64 = j-pair. memset-0 == t=0.
// Anti-overwrite induction as r9-r16 (verify of (t,b) proves all peers' (t-1,b)
// reads completed -> storing (t+1,b) over (t-1,b) is safe). Agent-scope relaxed.
__global__ __launch_bounds__(NTH, 6)
void k_rnn(const int* __restrict__ tokens, const float* __restrict__ whh,
           const float* __restrict__ gtab, const float* __restrict__ bhh,
           unsigned* __restrict__ hbuf, float* __restrict__ hout) {
    const int R   = blockIdx.x & (NREP - 1);
    const int wg  = blockIdx.x >> 5;
    const int tid = threadIdx.x;
    const int jl  = tid >> 4;                  // 0..47
    const int q   = tid & 15;                  // k-slice
    const int j   = wg * JPW + jl;

    __shared__ __align__(16) _Float16 hlds[BPR * 16 * 56];  // [b][q][48+8pad] = 3584 B

    // ---- one-time: weight slice -> 18 statically-indexed f16x8 (72 VGPRs)
    F16x8 w[3][6];
#pragma unroll
    for (int g = 0; g < 3; ++g) {
        const float4* s4 = (const float4*)(whh + (size_t)(g * HN + j) * HN + q * 48);
#pragma unroll
        for (int c = 0; c < 6; ++c) {
            float4 a = s4[2 * c], b4 = s4[2 * c + 1];
            F16x8 t;
            t.v[0] = (_Float16)a.x;  t.v[1] = (_Float16)a.y;
            t.v[2] = (_Float16)a.z;  t.v[3] = (_Float16)a.w;
            t.v[4] = (_Float16)b4.x; t.v[5] = (_Float16)b4.y;
            t.v[6] = (_Float16)b4.z; t.v[7] = (_Float16)b4.w;
            w[g][c] = t;
        }
    }

    const float bhr = bhh[j], bhz = bhh[HN + j], bhn = bhh[2 * HN + j];
    u64* hb2 = (u64*)hbuf + (size_t)R * (2 * BPR * 384);
    // poller deposit ptr: u64 word tid covers global j-pair (2*tid, 2*tid+1)
    unsigned short* dep = (unsigned short*)hlds + (tid / 24) * 56 + (tid % 24) * 2;

    float hprev = 0.f;
    float xr = 0.f, xz = 0.f, xn = 0.f, xrn = 0.f, xzn = 0.f, xnn = 0.f;
    if (q < BPR) {                           // x-gates for t=0 (owner q handles batch q)
        const int tok = tokens[(size_t)(R * BPR + q) * TN + 0];
        const float* g_ = gtab + (size_t)tok * H3N;
        xr = g_[j]; xz = g_[HN + j]; xn = g_[2 * HN + j];
    }

    // depth-2 poll ring prologue: stages (0,0) and (0,1)
    u64 vcur = 0, vnxt = 0;
    if (tid < 384) {
        vcur = __hip_atomic_load(hb2 + 0 * 384 + tid, __ATOMIC_RELAXED, __HIP_MEMORY_SCOPE_AGENT);
        vnxt = __hip_atomic_load(hb2 + 1 * 384 + tid, __ATOMIC_RELAXED, __HIP_MEMORY_SCOPE_AGENT);
    }

#pragma unroll 1
    for (int t = 0; t < TN; ++t) {
        const u64 want_pair = ((u64)(unsigned)t << 16) | ((u64)(unsigned)t << 48);
#pragma unroll
        for (int b = 0; b < BPR; ++b) {
            // ---- verify (self-adjusting steady state) + deposit (one v_perm pack)
            if (tid < 384) {
                const u64* cur = hb2 + ((t & 1) * BPR + b) * 384 + tid;
                while ((vcur & 0xFFFF0000FFFF0000ull) != want_pair) {
                    __builtin_amdgcn_s_sleep(1);
                    vcur = __hip_atomic_load(cur, __ATOMIC_RELAXED, __HIP_MEMORY_SCOPE_AGENT);
                }
                *(unsigned*)(dep + b * 896) =
                    __builtin_amdgcn_perm((unsigned)(vcur >> 32), (unsigned)vcur, 0x05040100);
            }
            barrier_lgkm();                  // tile b visible; polls stay in flight

            // ---- rotate ring: issue poll load for stage s+2 (= same b, step t+1)
            if (tid < 384) {
                int b2 = b + 2;
                const int t2 = t + (b2 >> 1);
                b2 &= 1;
                u64 vnew = 0;
                if (t2 < TN)
                    vnew = __hip_atomic_load(hb2 + ((t2 & 1) * BPR + b2) * 384 + tid,
                                             __ATOMIC_RELAXED, __HIP_MEMORY_SCOPE_AGENT);
                vcur = vnxt;
                vnxt = vnew;
            }
            // ---- prefetch next step's x-gates during stage 0
            if (b == 0 && q < BPR && t < TN - 1) {
                const int tok = tokens[(size_t)(R * BPR + q) * TN + (t + 1)];
                const float* g_ = gtab + (size_t)tok * H3N;
                xrn = g_[j]; xzn = g_[HN + j]; xnn = g_[2 * HN + j];
            }

            // ---- dot: 72 fdot2 from VGPR weights, 16-lane DPP reduce
            float ar = 0.f, az = 0.f, an = 0.f;
            const f16x8* hp = (const f16x8*)(hlds + b * 896 + q * 56);
#pragma unroll
            for (int c = 0; c < 6; ++c) {
                F16x8 hh; hh.v = hp[c];
#pragma unroll
                for (int p = 0; p < 4; ++p) {
                    ar = fdot2(w[0][c].p[p], hh.p[p], ar);
                    az = fdot2(w[1][c].p[p], hh.p[p], az);
                    an = fdot2(w[2][c].p[p], hh.p[p], an);
                }
            }
            const float sr = hexsum(ar), sz = hexsum(az), sn = hexsum(an);

            // ---- gate on owner lanes (q == b), paired tagged store
            unsigned pk = 0;
            if (q == b) {
                const float r  = 1.f / (1.f + __expf(-(xr + sr + bhr)));
                const float z  = 1.f / (1.f + __expf(-(xz + sz + bhz)));
                const float nx = xn + r * (sn + bhn);
                const float n  = 1.f - 2.f / (__expf(2.f * nx) + 1.f);   // tanh
                hprev = (1.f - z) * n + z * hprev;
                pk = ((unsigned)(t + 1) << 16)
                   | (unsigned)__builtin_bit_cast(unsigned short, (_Float16)hprev);
            }
            const unsigned pk2 = __shfl_down(pk, 16, 64);   // pair jl with jl+1
            if (q == b) {
                if (t < TN - 1) {
                    if (!(jl & 1))
                        __hip_atomic_store(
                            hb2 + (((t + 1) & 1) * BPR + b) * 384 + wg * 24 + (jl >> 1),
                            (u64)pk | ((u64)pk2 << 32),
                            __ATOMIC_RELAXED, __HIP_MEMORY_SCOPE_AGENT);
                } else {
                    hout[(size_t)(R * BPR + b) * HN + j] = hprev;
                }
            }
        }
        xr = xrn; xz = xzn; xn = xnn;
    }
}

// ---------------- K3: logits + log_softmax
__global__ void k_logits(const float* __restrict__ hfin, const float* __restrict__ wout,
                         const float* __restrict__ bout, float* __restrict__ lp) {
    const int b = blockIdx.x;
    const int o = threadIdx.x / 64;
    const int lane = threadIdx.x % 64;
    const float* hrow = hfin + (size_t)b * HN;
    const float* w = wout + (size_t)o * HN;
    float p = 0.f;
    for (int k = lane; k < HN; k += 64) p += hrow[k] * w[k];
    for (int off = 32; off > 0; off >>= 1) p += __shfl_down(p, off, 64);
    __shared__ float lg[ON];
    if (lane == 0) lg[o] = p + bout[o];
    __syncthreads();
    if (threadIdx.x == 0) {
        float m = fmaxf(lg[0], fmaxf(lg[1], lg[2]));
        float s = __expf(lg[0] - m) + __expf(lg[1] - m) + __expf(lg[2] - m);
        float ls = __logf(s);
        lp[b * ON + 0] = lg[0] - m - ls;
        lp[b * ON + 1] = lg[1] - m - ls;
        lp[b * ON + 2] = lg[2] - m - ls;
    }
}

extern "C" void kernel_launch(void* const* d_in, const int* in_sizes, int n_in,
                              void* d_out, int out_size, void* d_ws, size_t ws_size,
                              hipStream_t stream) {
    const int*   tokens = (const int*)d_in[0];
    // d_in[1] = hidden: reference zeroes it, ignored.
    const float* embed  = (const float*)d_in[2];
    const float* wih    = (const float*)d_in[3];
    const float* whh    = (const float*)d_in[4];
    const float* bih    = (const float*)d_in[5];
    const float* bhh    = (const float*)d_in[6];
    const float* wout   = (const float*)d_in[7];
    const float* bout   = (const float*)d_in[8];

    float* out = (float*)d_out;                  // [B*O logprobs][B*H h_final]
    char* ws = (char*)d_ws;
    const size_t GTAB_OFF = 0;                   // 401*2304*4 = 3,695,616
    const size_t HBUF_OFF = 3695616;             // 32*2*2*384*8 = 393,216 (tagged u64)
    float*    gtab = (float*)(ws + GTAB_OFF);
    unsigned* hbuf = (unsigned*)(ws + HBUF_OFF);

    // tag protocol requires tag==0 / h==0 state on EVERY launch (graph-replayed)
    hipMemsetAsync(ws + HBUF_OFF, 0, 393216, stream);

    hipLaunchKernelGGL(k_build_gtab, dim3(H3N / 64, 16), dim3(256), 0, stream,
                       embed, wih, bih, gtab);
    hipLaunchKernelGGL(k_rnn, dim3(NREP * WGPR), dim3(NTH), 0, stream,
                       tokens, whh, gtab, bhh, hbuf, out + BN * ON);
    hipLaunchKernelGGL(k_logits, dim3(BN), dim3(192), 0, stream,
                       out + BN * ON, wout, bout, out);
}

// Round 20
// 4745.632 us; speedup vs baseline: 3.5069x; 3.4798x over previous
//
#include <hip/hip_runtime.h>

#define VOCABN 401
#define EN 256
#define HN 768
#define H3N 2304
#define ON 3
#define BN 64
#define TN 1024

// 16 replicas x 16 WGs; WG = 768 threads: 48 j's x 16 k-slices; 4 staged batches
#define NREP 16
#define WGPR 16
#define BPR  4
#define JPW  48
#define NTH  768

typedef _Float16 f16x2 __attribute__((ext_vector_type(2)));
typedef _Float16 f16x8 __attribute__((ext_vector_type(8)));
typedef unsigned long long u64;
union F16x8 { f16x8 v; f16x2 p[4]; };

__device__ __forceinline__ float fdot2(f16x2 a, f16x2 b, float c) {
#if __has_builtin(__builtin_amdgcn_fdot2)
    return __builtin_amdgcn_fdot2(a, b, c, false);
#else
    return c + (float)a[0] * (float)b[0] + (float)a[1] * (float)b[1];
#endif
}

// workgroup barrier that drains ONLY lgkm (LDS) — in-flight global (poll) loads
// survive the barrier. This is the key to keeping sync off the critical path.
__device__ __forceinline__ void barrier_lgkm() {
    asm volatile("s_waitcnt lgkmcnt(0)\n\ts_barrier" ::: "memory");
}

// sum across each aligned 16-lane group; pure-VALU DPP butterfly.
__device__ __forceinline__ float hexsum(float x) {
    int v = __builtin_bit_cast(int, x);
    x += __builtin_bit_cast(float, __builtin_amdgcn_update_dpp(0, v, 0xB1, 0xF, 0xF, true));
    v = __builtin_bit_cast(int, x);
    x += __builtin_bit_cast(float, __builtin_amdgcn_update_dpp(0, v, 0x4E, 0xF, 0xF, true));
    v = __builtin_bit_cast(int, x);
    x += __builtin_bit_cast(float, __builtin_amdgcn_update_dpp(0, v, 0x141, 0xF, 0xF, true));
    v = __builtin_bit_cast(int, x);
    x += __builtin_bit_cast(float, __builtin_amdgcn_update_dpp(0, v, 0x140, 0xF, 0xF, true));
    return x;
}

// ---------------- K1: gtab[v][g] = dot(embed[v], W_ih[g]) + b_ih[g]  (w-stationary)
__global__ __launch_bounds__(256)
void k_build_gtab(const float* __restrict__ embed, const float* __restrict__ wih,
                  const float* __restrict__ bih, float* __restrict__ gtab) {
    const int g  = blockIdx.x * 64 + (threadIdx.x >> 2);
    const int ql = threadIdx.x & 3;
    const int v0 = blockIdx.y * 26;
    const int v1 = min(VOCABN, v0 + 26);
    float4 w[16];
    const float4* s4 = (const float4*)(wih + (size_t)g * EN + ql * 64);
#pragma unroll
    for (int i = 0; i < 16; ++i) w[i] = s4[i];
    const float bias = bih[g];
    for (int v = v0; v < v1; ++v) {
        const float4* e4 = (const float4*)(embed + (size_t)v * EN + ql * 64);
        float acc = 0.f;
#pragma unroll
        for (int i = 0; i < 16; ++i) {
            float4 e = e4[i];
            acc += w[i].x * e.x + w[i].y * e.y + w[i].z * e.z + w[i].w * e.w;
        }
        acc += __shfl_xor(acc, 1, 64);
        acc += __shfl_xor(acc, 2, 64);
        if (ql == 0) gtab[(size_t)v * H3N + g] = acc + bias;
    }
}

// ---------------- K2: persistent-weight recurrence; batch-staggered pipeline,
// depth-2 poll ring, lgkm-only barriers (polls stay in flight across stages).
// h word (u32): [31:16]=step tag, [15:0]=f16 bits; u64 = j-pair. memset-0 == t=0.
// Stage (t,b): verify vcur (first-try in steady state) + v_perm deposit | bar(lgkm)
// | rotate ring (issue load for stage+2) | dot(b) | DPP-reduce | gate on owner
// lanes q==b | paired tagged store. Anti-overwrite induction: verify of (t,b)
// proves all peers stored (t,b), which (program order) proves their (t-1,b) reads
// completed -> storing (t+1,b) over (t-1,b) is safe. Agent-scope relaxed atomics.
__global__ __launch_bounds__(NTH, 1)
void k_rnn(const int* __restrict__ tokens, const float* __restrict__ whh,
           const float* __restrict__ gtab, const float* __restrict__ bhh,
           unsigned* __restrict__ hbuf, float* __restrict__ hout) {
    const int R   = blockIdx.x & (NREP - 1);
    const int wg  = blockIdx.x >> 4;
    const int tid = threadIdx.x;
    const int jl  = tid >> 4;                  // 0..47
    const int q   = tid & 15;                  // k-slice
    const int j   = wg * JPW + jl;

    __shared__ __align__(16) _Float16 hlds[BPR * 16 * 56];  // [b][q][48+8pad] = 7168 B

    // ---- one-time: weight slice -> 18 statically-indexed f16x8 (72 VGPRs)
    F16x8 w[3][6];
#pragma unroll
    for (int g = 0; g < 3; ++g) {
        const float4* s4 = (const float4*)(whh + (size_t)(g * HN + j) * HN + q * 48);
#pragma unroll
        for (int c = 0; c < 6; ++c) {
            float4 a = s4[2 * c], b4 = s4[2 * c + 1];
            F16x8 t;
            t.v[0] = (_Float16)a.x;  t.v[1] = (_Float16)a.y;
            t.v[2] = (_Float16)a.z;  t.v[3] = (_Float16)a.w;
            t.v[4] = (_Float16)b4.x; t.v[5] = (_Float16)b4.y;
            t.v[6] = (_Float16)b4.z; t.v[7] = (_Float16)b4.w;
            w[g][c] = t;
        }
    }

    const float bhr = bhh[j], bhz = bhh[HN + j], bhn = bhh[2 * HN + j];
    u64* hb2 = (u64*)hbuf + (size_t)R * (2 * BPR * 384);
    // poller deposit ptr: u64 word tid covers global j-pair (2*tid, 2*tid+1)
    unsigned short* dep = (unsigned short*)hlds + (tid / 24) * 56 + (tid % 24) * 2;

    float hprev = 0.f;
    float xr = 0.f, xz = 0.f, xn = 0.f, xrn = 0.f, xzn = 0.f, xnn = 0.f;
    if (q < BPR) {                           // x-gates for t=0 (owner q handles batch q)
        const int tok = tokens[(size_t)(R * BPR + q) * TN + 0];
        const float* g_ = gtab + (size_t)tok * H3N;
        xr = g_[j]; xz = g_[HN + j]; xn = g_[2 * HN + j];
    }

    // depth-2 poll ring prologue: stages (0,0) and (0,1)
    u64 vcur = 0, vnxt = 0;
    if (tid < 384) {
        vcur = __hip_atomic_load(hb2 + 0 * 384 + tid, __ATOMIC_RELAXED, __HIP_MEMORY_SCOPE_AGENT);
        vnxt = __hip_atomic_load(hb2 + 1 * 384 + tid, __ATOMIC_RELAXED, __HIP_MEMORY_SCOPE_AGENT);
    }

#pragma unroll 1
    for (int t = 0; t < TN; ++t) {
        const u64 want_pair = ((u64)(unsigned)t << 16) | ((u64)(unsigned)t << 48);
#pragma unroll
        for (int b = 0; b < BPR; ++b) {
            // ---- verify (first-try in steady state) + deposit (one v_perm pack)
            if (tid < 384) {
                const u64* cur = hb2 + ((t & 1) * BPR + b) * 384 + tid;
                while ((vcur & 0xFFFF0000FFFF0000ull) != want_pair) {
                    __builtin_amdgcn_s_sleep(1);
                    vcur = __hip_atomic_load(cur, __ATOMIC_RELAXED, __HIP_MEMORY_SCOPE_AGENT);
                }
                *(unsigned*)(dep + b * 896) =
                    __builtin_amdgcn_perm((unsigned)(vcur >> 32), (unsigned)vcur, 0x05040100);
            }
            barrier_lgkm();                  // tile b visible; polls stay in flight

            // ---- rotate ring: issue poll load for stage s+2
            if (tid < 384) {
                int b2 = b + 2;
                const int t2 = t + (b2 >> 2);
                b2 &= 3;
                u64 vnew = 0;
                if (t2 < TN)
                    vnew = __hip_atomic_load(hb2 + ((t2 & 1) * BPR + b2) * 384 + tid,
                                             __ATOMIC_RELAXED, __HIP_MEMORY_SCOPE_AGENT);
                vcur = vnxt;
                vnxt = vnew;
            }
            // ---- prefetch next step's x-gates during stage 0 (4 stages of slack)
            if (b == 0 && q < BPR && t < TN - 1) {
                const int tok = tokens[(size_t)(R * BPR + q) * TN + (t + 1)];
                const float* g_ = gtab + (size_t)tok * H3N;
                xrn = g_[j]; xzn = g_[HN + j]; xnn = g_[2 * HN + j];
            }

            // ---- dot: 72 fdot2 from VGPR weights, 16-lane DPP reduce
            float ar = 0.f, az = 0.f, an = 0.f;
            const f16x8* hp = (const f16x8*)(hlds + b * 896 + q * 56);
#pragma unroll
            for (int c = 0; c < 6; ++c) {
                F16x8 hh; hh.v = hp[c];
#pragma unroll
                for (int p = 0; p < 4; ++p) {
                    ar = fdot2(w[0][c].p[p], hh.p[p], ar);
                    az = fdot2(w[1][c].p[p], hh.p[p], az);
                    an = fdot2(w[2][c].p[p], hh.p[p], an);
                }
            }
            const float sr = hexsum(ar), sz = hexsum(az), sn = hexsum(an);

            // ---- gate on owner lanes (q == b), paired tagged store
            unsigned pk = 0;
            if (q == b) {
                const float r  = 1.f / (1.f + __expf(-(xr + sr + bhr)));
                const float z  = 1.f / (1.f + __expf(-(xz + sz + bhz)));
                const float nx = xn + r * (sn + bhn);
                const float n  = 1.f - 2.f / (__expf(2.f * nx) + 1.f);   // tanh
                hprev = (1.f - z) * n + z * hprev;
                pk = ((unsigned)(t + 1) << 16)
                   | (unsigned)__builtin_bit_cast(unsigned short, (_Float16)hprev);
            }
            const unsigned pk2 = __shfl_down(pk, 16, 64);   // pair jl with jl+1
            if (q == b) {
                if (t < TN - 1) {
                    if (!(jl & 1))
                        __hip_atomic_store(
                            hb2 + (((t + 1) & 1) * BPR + b) * 384 + wg * 24 + (jl >> 1),
                            (u64)pk | ((u64)pk2 << 32),
                            __ATOMIC_RELAXED, __HIP_MEMORY_SCOPE_AGENT);
                } else {
                    hout[(size_t)(R * BPR + b) * HN + j] = hprev;
                }
            }
        }
        xr = xrn; xz = xzn; xn = xnn;
    }
}

// ---------------- K3: logits + log_softmax
__global__ void k_logits(const float* __restrict__ hfin, const float* __restrict__ wout,
                         const float* __restrict__ bout, float* __restrict__ lp) {
    const int b = blockIdx.x;
    const int o = threadIdx.x / 64;
    const int lane = threadIdx.x % 64;
    const float* hrow = hfin + (size_t)b * HN;
    const float* w = wout + (size_t)o * HN;
    float p = 0.f;
    for (int k = lane; k < HN; k += 64) p += hrow[k] * w[k];
    for (int off = 32; off > 0; off >>= 1) p += __shfl_down(p, off, 64);
    __shared__ float lg[ON];
    if (lane == 0) lg[o] = p + bout[o];
    __syncthreads();
    if (threadIdx.x == 0) {
        float m = fmaxf(lg[0], fmaxf(lg[1], lg[2]));
        float s = __expf(lg[0] - m) + __expf(lg[1] - m) + __expf(lg[2] - m);
        float ls = __logf(s);
        lp[b * ON + 0] = lg[0] - m - ls;
        lp[b * ON + 1] = lg[1] - m - ls;
        lp[b * ON + 2] = lg[2] - m - ls;
    }
}

extern "C" void kernel_launch(void* const* d_in, const int* in_sizes, int n_in,
                              void* d_out, int out_size, void* d_ws, size_t ws_size,
                              hipStream_t stream) {
    const int*   tokens = (const int*)d_in[0];
    // d_in[1] = hidden: reference zeroes it, ignored.
    const float* embed  = (const float*)d_in[2];
    const float* wih    = (const float*)d_in[3];
    const float* whh    = (const float*)d_in[4];
    const float* bih    = (const float*)d_in[5];
    const float* bhh    = (const float*)d_in[6];
    const float* wout   = (const float*)d_in[7];
    const float* bout   = (const float*)d_in[8];

    float* out = (float*)d_out;                  // [B*O logprobs][B*H h_final]
    char* ws = (char*)d_ws;
    const size_t GTAB_OFF = 0;                   // 401*2304*4 = 3,695,616
    const size_t HBUF_OFF = 3695616;             // 16*2*4*384*8 = 393,216 (tagged u64)
    float*    gtab = (float*)(ws + GTAB_OFF);
    unsigned* hbuf = (unsigned*)(ws + HBUF_OFF);

    // tag protocol requires tag==0 / h==0 state on EVERY launch (graph-replayed)
    hipMemsetAsync(ws + HBUF_OFF, 0, 393216, stream);

    hipLaunchKernelGGL(k_build_gtab, dim3(H3N / 64, 16), dim3(256), 0, stream,
                       embed, wih, bih, gtab);
    hipLaunchKernelGGL(k_rnn, dim3(NREP * WGPR), dim3(NTH), 0, stream,
                       tokens, whh, gtab, bhh, hbuf, out + BN * ON);
    hipLaunchKernelGGL(k_logits, dim3(BN), dim3(192), 0, stream,
                       out + BN * ON, wout, bout, out);
}